// Round 3
// baseline (268.268 us; speedup 1.0000x reference)
//
#include <hip/hip_runtime.h>
#include <hip/hip_bf16.h>

// QuantLinear: out[t,o] = scale[o] * sum_k x[t,k]*q[o,k] + bias[o]
// M=32, N=11008, K=4096. x/scales/bias/out fp32, qweight int32 (int8 vals).
// 180.4 MB weight stream -> 28.6 us floor @6.3 TB/s.
//
// Round-7: kill the vmcnt(0) sawtooth. Rounds 0-2 drained every wave's
// DMA to zero in-flight once per 8 KB chunk (barrier-forced vmcnt(0)),
// convoying all waves into dead windows -> ~4.7 TB/s weight stream.
// Now: per-wave DOUBLE-BUFFERED 4 KB chunks (CK=64) with counted
// `s_waitcnt vmcnt(4)` -- chunk c+1 always in flight while chunk c is
// consumed (T3/T4: never drain to 0 in the main loop). No main-loop
// barriers: chunks are wave-private; the overwrite hazard (ds_read of
// chunk c vs DMA of chunk c+2 into the same buffer) is closed because
// the compiler's lgkmcnt waits before chunk c's MFMAs retire all
// ds_reads before the (program-order later) DMA issue.

constexpr int IN_F   = 4096;
constexpr int OUT_F  = 11008;
constexpr int KSLICE = 1024;           // per-wave K range (4-way K-split)
constexpr int CK     = 64;             // K ints per chunk (256 B per row)
constexpr int NCHUNK = KSLICE / CK;    // 16 chunks per wave

typedef short bf16x8 __attribute__((ext_vector_type(8)));  // 8 bf16
typedef float f32x4  __attribute__((ext_vector_type(4)));

union B8 { bf16x8 v; unsigned u[4]; };

// [hi16(lo), hi16(hi)] -> bf16 pair (truncate). Exact for int8 values.
__device__ __forceinline__ unsigned pack2f(float lo, float hi) {
    return __builtin_amdgcn_perm(__float_as_uint(hi),
                                 __float_as_uint(lo),
                                 0x07060302u);
}

// x fp32 -> bf16 (truncate) into workspace. 131072 elems.
__global__ __launch_bounds__(256)
void xconv_kernel(const float* __restrict__ x, unsigned* __restrict__ xb) {
    const int i = (blockIdx.x * 256 + threadIdx.x) * 4;
    float4 v = *reinterpret_cast<const float4*>(x + i);
    xb[i / 2]     = pack2f(v.x, v.y);
    xb[i / 2 + 1] = pack2f(v.z, v.w);
}

__global__ __launch_bounds__(256, 4)   // 4 blocks/CU (LDS 38.9 KB, VGPR<=128)
void qlin_kernel(const unsigned short* __restrict__ xb,  // bf16 bits [32][4096]
                 const int* __restrict__ w,              // int32 [11008][4096]
                 const float* __restrict__ scales,       // [11008]
                 const float* __restrict__ bias,         // [11008]
                 float* __restrict__ out)                // [32][11008]
{
    __shared__ int   wbuf[4][2][CK * 16];     // 4 waves x 2 x 4 KB chunks
    __shared__ float red[3][2][4][64];        // cross-wave reduction

    const int lane = threadIdx.x & 63;
    const int wv   = threadIdx.x >> 6;   // 0..3: K-split across 4 waves
    const int r    = lane & 15;
    const int q    = lane >> 4;

    const int n0 = blockIdx.x << 4;      // 688 blocks x 16 output rows
    const int kb = wv * KSLICE;

    f32x4 acc0 = {0.f, 0.f, 0.f, 0.f};   // tokens 0..15
    f32x4 acc1 = {0.f, 0.f, 0.f, 0.f};   // tokens 16..31

    // A-frags from global (L2-resident bf16 x), 16B per lane
    const unsigned short* xp0 = xb + r * IN_F + kb + q * 8;
    const unsigned short* xp1 = xp0 + 16 * IN_F;

    // LDS read view: row r at byte offset r*256 within this wave's chunk;
    // group slot s holds k-group g where s = g ^ (r&7)  (bank spread:
    // 16 lanes/quarter -> 8 distinct 16B slots -> 2-way, free).
    const int swz = r & 7;

    // Weight DMA for one 4 KB chunk: 4 x 1KB instructions. Instr j covers
    // rows 4j..4j+3 (256B each). LDS dst = uniform base + lane*16 lands
    // lane l at row 4j+(l>>4), slot (l&15). Global source pre-swizzled so
    // slot s holds group g = s ^ (row&7).
    auto issue_dma = [&](int c, int b) {
        const int kc = kb + c * CK;
        #pragma unroll
        for (int j = 0; j < 4; ++j) {
            const int rj = 4 * j + (lane >> 4);
            const int gj = (lane & 15) ^ (rj & 7);
            const int* src = w + (size_t)(n0 + rj) * IN_F + kc + 4 * gj;
            __builtin_amdgcn_global_load_lds(
                (const __attribute__((address_space(1))) void*)src,
                (__attribute__((address_space(3))) void*)&wbuf[wv][b][j * 256],
                16, 0, 0);
        }
    };

    // Prologue: chunk 0 in flight.
    issue_dma(0, 0);

    #pragma unroll
    for (int c = 0; c < NCHUNK; ++c) {
        // A-frag loads FIRST (so the compiler's af-wait is vmcnt(4), not 0).
        bf16x8 af0[2], af1[2];
        #pragma unroll
        for (int i = 0; i < 2; ++i) {
            af0[i] = *reinterpret_cast<const bf16x8*>(xp0 + c * CK + i * 32);
            af1[i] = *reinterpret_cast<const bf16x8*>(xp1 + c * CK + i * 32);
        }
        asm volatile("" ::: "memory");   // pin: af issue before next DMA

        if (c + 1 < NCHUNK) {
            issue_dma(c + 1, (c + 1) & 1);
            // Chunk c + af landed; chunk c+1's 4 loads stay in flight.
            asm volatile("s_waitcnt vmcnt(4)" ::: "memory");
        } else {
            asm volatile("s_waitcnt vmcnt(0)" ::: "memory");
        }
        __builtin_amdgcn_sched_barrier(0);

        const int4* lsp =
            reinterpret_cast<const int4*>(&wbuf[wv][c & 1][0]) + r * 16;
        #pragma unroll
        for (int i = 0; i < 2; ++i) {
            const int G0 = i * 8 + q * 2;          // 16B k-group index
            int4 qa = lsp[G0 ^ swz];
            int4 qb = lsp[(G0 + 1) ^ swz];
            B8 bb;
            bb.u[0] = pack2f((float)qa.x, (float)qa.y);
            bb.u[1] = pack2f((float)qa.z, (float)qa.w);
            bb.u[2] = pack2f((float)qb.x, (float)qb.y);
            bb.u[3] = pack2f((float)qb.z, (float)qb.w);
            acc0 = __builtin_amdgcn_mfma_f32_16x16x32_bf16(af0[i], bb.v, acc0, 0, 0, 0);
            acc1 = __builtin_amdgcn_mfma_f32_16x16x32_bf16(af1[i], bb.v, acc1, 0, 0, 0);
        }
    }

    // Cross-wave K reduction through LDS.
    if (wv > 0) {
        #pragma unroll
        for (int i = 0; i < 4; ++i) {
            red[wv - 1][0][i][lane] = acc0[i];
            red[wv - 1][1][i][lane] = acc1[i];
        }
    }
    __syncthreads();
    if (wv == 0) {
        #pragma unroll
        for (int j = 0; j < 3; ++j) {
            #pragma unroll
            for (int i = 0; i < 4; ++i) {
                acc0[i] += red[j][0][i][lane];
                acc1[i] += red[j][1][i][lane];
            }
        }
        // C/D layout (m89/m91): col n = lane&15, row m = (lane>>4)*4 + reg
        const int n = n0 + r;
        const float s = scales[n];
        const float b = bias[n];
        #pragma unroll
        for (int i = 0; i < 4; ++i) {
            out[(q * 4 + i) * OUT_F + n]      = acc0[i] * s + b;
            out[(16 + q * 4 + i) * OUT_F + n] = acc1[i] * s + b;
        }
    }
}

extern "C" void kernel_launch(void* const* d_in, const int* in_sizes, int n_in,
                              void* d_out, int out_size, void* d_ws, size_t ws_size,
                              hipStream_t stream) {
    const float* x      = (const float*)d_in[0];
    const int*   w      = (const int*)d_in[1];
    const float* scales = (const float*)d_in[2];
    const float* bias   = (const float*)d_in[3];
    float*       out    = (float*)d_out;
    unsigned*    xb     = (unsigned*)d_ws;   // bf16 x, 256 KB

    xconv_kernel<<<dim3(32 * IN_F / (256 * 4)), dim3(256), 0, stream>>>(x, xb);
    qlin_kernel<<<dim3(OUT_F / 16), dim3(256), 0, stream>>>(
        (const unsigned short*)xb, w, scales, bias, out);
}

// Round 4
// 252.681 us; speedup vs baseline: 1.0617x; 1.0617x over previous
//
#include <hip/hip_runtime.h>
#include <hip/hip_bf16.h>

// QuantLinear: out[t,o] = scale[o] * sum_k x[t,k]*q[o,k] + bias[o]
// M=32, N=11008, K=4096. x/scales/bias/out fp32, qweight int32 (int8 vals).
// 180.4 MB weight stream -> 29 us floor @6.3 TB/s.
// Round-8: REVERT to the session-best structure (251.9 us). Weights staged
// via global_load_lds (outstanding bytes cost no VGPRs -> ~85 KB/CU in
// flight vs 9.2 KB Little's-law need). Per-wave private 8 KB chunks, XOR
// bank swizzle (2-way conflicts, free), barrier per chunk phase
// (compiler-guaranteed vmcnt drain, m97 pattern).
// Falsified this session: residency-tail (256-thr/4-blk: flat),
// barrier-removal (worse), counted-vmcnt dbuf (worse). The ~209 us of
// harness re-poison fills at 86% HBM peak dominates the window; qlin's
// weight stream runs at ~80-85% of achievable read BW.

constexpr int IN_F   = 4096;
constexpr int OUT_F  = 11008;
constexpr int KSLICE = 512;            // per-wave K range (8-way K-split)
constexpr int CK     = 128;            // K ints per chunk (512 B per row)

typedef short bf16x8 __attribute__((ext_vector_type(8)));  // 8 bf16
typedef float f32x4  __attribute__((ext_vector_type(4)));

union B8 { bf16x8 v; unsigned u[4]; };

// [hi16(lo), hi16(hi)] -> bf16 pair (truncate). Exact for int8 values.
__device__ __forceinline__ unsigned pack2f(float lo, float hi) {
    return __builtin_amdgcn_perm(__float_as_uint(hi),
                                 __float_as_uint(lo),
                                 0x07060302u);
}

// x fp32 -> bf16 (truncate) into workspace. 131072 elems.
__global__ __launch_bounds__(256)
void xconv_kernel(const float* __restrict__ x, unsigned* __restrict__ xb) {
    const int i = (blockIdx.x * 256 + threadIdx.x) * 4;
    float4 v = *reinterpret_cast<const float4*>(x + i);
    xb[i / 2]     = pack2f(v.x, v.y);
    xb[i / 2 + 1] = pack2f(v.z, v.w);
}

__global__ __launch_bounds__(512, 4)   // 2 blocks/CU (also LDS-capped: 78 KB)
void qlin_kernel(const unsigned short* __restrict__ xb,  // bf16 bits [32][4096]
                 const int* __restrict__ w,              // int32 [11008][4096]
                 const float* __restrict__ scales,       // [11008]
                 const float* __restrict__ bias,         // [11008]
                 float* __restrict__ out)                // [32][11008]
{
    __shared__ int   wbuf[8][CK * 16];        // 8 waves x 8 KB weight chunk
    __shared__ float red[7][2][4][64];        // cross-wave reduction

    const int lane = threadIdx.x & 63;
    const int wv   = threadIdx.x >> 6;   // 0..7: K-split across 8 waves
    const int r    = lane & 15;
    const int q    = lane >> 4;

    const int n0 = blockIdx.x << 4;      // 688 blocks x 16 output rows
    const int kb = wv * KSLICE;

    f32x4 acc0 = {0.f, 0.f, 0.f, 0.f};   // tokens 0..15
    f32x4 acc1 = {0.f, 0.f, 0.f, 0.f};   // tokens 16..31

    // A-frags from global (L2-resident bf16 x), 16B per lane
    const unsigned short* xp0 = xb + r * IN_F + kb + q * 8;
    const unsigned short* xp1 = xp0 + 16 * IN_F;

    // LDS read view: row r at byte offset r*512 within this wave's chunk;
    // group slot s holds k-group g where s = g ^ (r&7)  (bank spread).
    const int  swz = r & 7;
    const int4* lsp = reinterpret_cast<const int4*>(&wbuf[wv][0]) + r * 32;

    for (int c = 0; c < KSLICE / CK; ++c) {
        const int kc = kb + c * CK;
        // Weight DMA: 8 x 1KB dense instructions. Instr j covers rows
        // 2j,2j+1 (512B each). LDS dst = uniform base + lane*16, which
        // lands lane l's 16B at row (2j + l>>5), slot (l&31). We choose the
        // global source so slot s holds group g = s ^ (r&7).
        #pragma unroll
        for (int j = 0; j < 8; ++j) {
            const int rj = 2 * j + (lane >> 5);
            const int gj = (lane & 31) ^ (rj & 7);
            const int* src = w + (size_t)(n0 + rj) * IN_F + kc + 4 * gj;
            __builtin_amdgcn_global_load_lds(
                (const __attribute__((address_space(1))) void*)src,
                (__attribute__((address_space(3))) void*)&wbuf[wv][j * 256],
                16, 0, 0);
        }
        // A-frag prefetch for this chunk (completes during the DMA drain).
        bf16x8 af0[4], af1[4];
        #pragma unroll
        for (int i = 0; i < 4; ++i) {
            af0[i] = *reinterpret_cast<const bf16x8*>(xp0 + c * CK + i * 32);
            af1[i] = *reinterpret_cast<const bf16x8*>(xp1 + c * CK + i * 32);
        }
        __syncthreads();   // compiler emits vmcnt(0) drain: DMA complete

        #pragma unroll
        for (int i = 0; i < 4; ++i) {
            const int G0 = i * 8 + q * 2;          // 16B k-group index
            int4 qa = lsp[G0 ^ swz];
            int4 qb = lsp[(G0 + 1) ^ swz];
            B8 bb;
            bb.u[0] = pack2f((float)qa.x, (float)qa.y);
            bb.u[1] = pack2f((float)qa.z, (float)qa.w);
            bb.u[2] = pack2f((float)qb.x, (float)qb.y);
            bb.u[3] = pack2f((float)qb.z, (float)qb.w);
            acc0 = __builtin_amdgcn_mfma_f32_16x16x32_bf16(af0[i], bb.v, acc0, 0, 0, 0);
            acc1 = __builtin_amdgcn_mfma_f32_16x16x32_bf16(af1[i], bb.v, acc1, 0, 0, 0);
        }
        __syncthreads();   // all reads done before next chunk overwrites
    }

    // Cross-wave K reduction through LDS.
    if (wv > 0) {
        #pragma unroll
        for (int i = 0; i < 4; ++i) {
            red[wv - 1][0][i][lane] = acc0[i];
            red[wv - 1][1][i][lane] = acc1[i];
        }
    }
    __syncthreads();
    if (wv == 0) {
        #pragma unroll
        for (int j = 0; j < 7; ++j) {
            #pragma unroll
            for (int i = 0; i < 4; ++i) {
                acc0[i] += red[j][0][i][lane];
                acc1[i] += red[j][1][i][lane];
            }
        }
        // C/D layout (m89/m91): col n = lane&15, row m = (lane>>4)*4 + reg
        const int n = n0 + r;
        const float s = scales[n];
        const float b = bias[n];
        #pragma unroll
        for (int i = 0; i < 4; ++i) {
            out[(q * 4 + i) * OUT_F + n]      = acc0[i] * s + b;
            out[(16 + q * 4 + i) * OUT_F + n] = acc1[i] * s + b;
        }
    }
}

extern "C" void kernel_launch(void* const* d_in, const int* in_sizes, int n_in,
                              void* d_out, int out_size, void* d_ws, size_t ws_size,
                              hipStream_t stream) {
    const float* x      = (const float*)d_in[0];
    const int*   w      = (const int*)d_in[1];
    const float* scales = (const float*)d_in[2];
    const float* bias   = (const float*)d_in[3];
    float*       out    = (float*)d_out;
    unsigned*    xb     = (unsigned*)d_ws;   // bf16 x, 256 KB

    xconv_kernel<<<dim3(32 * IN_F / (256 * 4)), dim3(256), 0, stream>>>(x, xb);
    qlin_kernel<<<dim3(OUT_F / 16), dim3(512), 0, stream>>>(
        (const unsigned short*)xb, w, scales, bias, out);
}